// Round 1
// baseline (2242.380 us; speedup 1.0000x reference)
//
#include <hip/hip_runtime.h>
#include <hip/hip_bf16.h>

// Sizes: B=16, CIN=64, COUT=64, H=128, W=128. up: (16,64,256,256).
#define TOTAL_WPRE  (64 * 9 * 64 * 4)  // 147456 floats
#define TOTAL_WPOST (64 * 9 * 64)      // 36864 floats

// wpreT[((ci*9 + k)*64 + c)*4 + v] = w_pre[((v*64 + c)*64 + ci)*9 + k]
__global__ __launch_bounds__(256) void prep_wpre_k(const float* __restrict__ w_pre,
                                                   float* __restrict__ wpreT) {
  int i = blockIdx.x * 256 + threadIdx.x;
  if (i >= TOTAL_WPRE) return;
  int v  = i & 3;
  int c  = (i >> 2) & 63;
  int k  = (i >> 8) % 9;
  int ci = i / 2304;
  wpreT[i] = w_pre[((v * 64 + c) * 64 + ci) * 9 + k];
}

// wpostT[(ci*9 + k)*64 + co] = w_post[(co*64 + ci)*9 + k]
__global__ __launch_bounds__(256) void prep_wpost_k(const float* __restrict__ w_post,
                                                    float* __restrict__ wpostT) {
  int i = blockIdx.x * 256 + threadIdx.x;
  if (i >= TOTAL_WPOST) return;
  int co = i & 63;
  int k  = (i >> 6) % 9;
  int ci = i / 576;
  wpostT[i] = w_post[(co * 64 + ci) * 9 + k];
}

// Conv1 (64->256, 3x3 SAME) fused with wavelet combine + 2x upsample.
// Block: 256 thr = 16x16 spatial tile on the 128x128 grid; per-thread 4 c's x 4 quadrants.
__global__ __launch_bounds__(256) void conv1_wavelet_k(
    const float* __restrict__ x, const float* __restrict__ wpreT,
    const float* __restrict__ b_pre, __hip_bfloat16* __restrict__ up)
{
  __shared__ float lds[16][18][18];
  const int tid  = threadIdx.x;
  const int tile = blockIdx.x;        // 0..63 (8x8 tiles)
  const int cb   = blockIdx.y * 4;    // c base, 16 groups
  const int b    = blockIdx.z;
  const int ty   = tid >> 4;
  const int tx   = tid & 15;
  const int y0   = (tile >> 3) << 4;
  const int x0   = (tile & 7) << 4;

  float acc[4][4];
  #pragma unroll
  for (int u = 0; u < 4; ++u)
    #pragma unroll
    for (int v = 0; v < 4; ++v) acc[u][v] = 0.f;

  for (int cc = 0; cc < 4; ++cc) {    // cin chunks of 16
    __syncthreads();
    for (int idx = tid; idx < 5184; idx += 256) {  // 18*18*16
      int ci  = idx / 324;
      int rem = idx - ci * 324;
      int dy  = rem / 18;
      int dx  = rem - dy * 18;
      int gy  = y0 + dy - 1;
      int gx  = x0 + dx - 1;
      float val = 0.f;
      if ((unsigned)gy < 128u && (unsigned)gx < 128u)
        val = x[((b * 64 + cc * 16 + ci) * 128 + gy) * 128 + gx];
      lds[ci][dy][dx] = val;
    }
    __syncthreads();
    for (int ci = 0; ci < 16; ++ci) {
      #pragma unroll
      for (int k = 0; k < 9; ++k) {
        const int kh = k / 3, kw = k % 3;
        const float xv = lds[ci][ty + kh][tx + kw];
        // 16 consecutive floats at a block-uniform address -> scalar loads
        const float* wp = wpreT + (((cc * 16 + ci) * 9 + k) * 64 + cb) * 4;
        #pragma unroll
        for (int u = 0; u < 4; ++u)
          #pragma unroll
          for (int v = 0; v < 4; ++v)
            acc[u][v] = fmaf(xv, wp[u * 4 + v], acc[u][v]);
      }
    }
  }

  // Epilogue: bias + inverse-wavelet combine + 2x upsample, write bf16.
  const int gy = y0 + ty, gx = x0 + tx;
  #pragma unroll
  for (int u = 0; u < 4; ++u) {
    const int c = cb + u;
    const float a0 = acc[u][0] + b_pre[c];         // ll
    const float a1 = acc[u][1] + b_pre[64 + c];    // lh
    const float a2 = acc[u][2] + b_pre[128 + c];   // hl
    const float a3 = acc[u][3] + b_pre[192 + c];   // hh
    const float ee = 0.5f * (a0 + a1 + a2 + a3);
    const float eo = 0.5f * (a0 - a1 + a2 - a3);
    const float oe = 0.5f * (a0 + a1 - a2 - a3);
    const float oo = 0.5f * (a0 - a1 - a2 + a3);
    const int base = (((b * 64 + c) * 256 + 2 * gy) * 256) + 2 * gx;
    __hip_bfloat162 r0, r1;
    r0.x = __float2bfloat16(ee); r0.y = __float2bfloat16(eo);
    r1.x = __float2bfloat16(oe); r1.y = __float2bfloat16(oo);
    *reinterpret_cast<__hip_bfloat162*>(up + base)       = r0;
    *reinterpret_cast<__hip_bfloat162*>(up + base + 256) = r1;
  }
}

// Conv2 (64->64, 3x3 SAME) on up (16,64,256,256) bf16 -> out f32.
// Block: 256 thr = 16x16 spatial tile on the 256x256 grid; per-thread 16 co.
__global__ __launch_bounds__(256) void conv2_k(
    const __hip_bfloat16* __restrict__ up, const float* __restrict__ wpostT,
    const float* __restrict__ b_post, float* __restrict__ out)
{
  __shared__ float lds[16][18][18];
  const int tid  = threadIdx.x;
  const int tile = blockIdx.x;          // 0..255 (16x16 tiles)
  const int cob  = blockIdx.y * 16;     // 4 groups
  const int b    = blockIdx.z;
  const int ty   = tid >> 4;
  const int tx   = tid & 15;
  const int y0   = (tile >> 4) << 4;
  const int x0   = (tile & 15) << 4;

  float acc[16];
  #pragma unroll
  for (int o = 0; o < 16; ++o) acc[o] = 0.f;

  for (int cc = 0; cc < 4; ++cc) {
    __syncthreads();
    for (int idx = tid; idx < 5184; idx += 256) {
      int ci  = idx / 324;
      int rem = idx - ci * 324;
      int dy  = rem / 18;
      int dx  = rem - dy * 18;
      int gy  = y0 + dy - 1;
      int gx  = x0 + dx - 1;
      float val = 0.f;
      if ((unsigned)gy < 256u && (unsigned)gx < 256u)
        val = __bfloat162float(up[((b * 64 + cc * 16 + ci) * 256 + gy) * 256 + gx]);
      lds[ci][dy][dx] = val;
    }
    __syncthreads();
    for (int ci = 0; ci < 16; ++ci) {
      #pragma unroll
      for (int k = 0; k < 9; ++k) {
        const int kh = k / 3, kw = k % 3;
        const float xv = lds[ci][ty + kh][tx + kw];
        const float* wp = wpostT + ((cc * 16 + ci) * 9 + k) * 64 + cob;
        #pragma unroll
        for (int o = 0; o < 16; ++o)
          acc[o] = fmaf(xv, wp[o], acc[o]);
      }
    }
  }

  const int gy = y0 + ty, gx = x0 + tx;
  #pragma unroll
  for (int o = 0; o < 16; ++o)
    out[((b * 64 + cob + o) * 256 + gy) * 256 + gx] = acc[o] + b_post[cob + o];
}

extern "C" void kernel_launch(void* const* d_in, const int* in_sizes, int n_in,
                              void* d_out, int out_size, void* d_ws, size_t ws_size,
                              hipStream_t stream) {
  const float* x      = (const float*)d_in[0];
  const float* w_pre  = (const float*)d_in[1];
  const float* b_pre  = (const float*)d_in[2];
  const float* w_post = (const float*)d_in[3];
  const float* b_post = (const float*)d_in[4];
  float* out = (float*)d_out;

  // ws layout: wpreT (589824 B) | wpostT (147456 B) | up bf16 (134217728 B)
  char* ws = (char*)d_ws;
  float* wpreT  = (float*)ws;
  float* wpostT = (float*)(ws + 589824);
  __hip_bfloat16* up = (__hip_bfloat16*)(ws + 589824 + 147456);

  prep_wpre_k<<<(TOTAL_WPRE + 255) / 256, 256, 0, stream>>>(w_pre, wpreT);
  prep_wpost_k<<<(TOTAL_WPOST + 255) / 256, 256, 0, stream>>>(w_post, wpostT);

  dim3 g1(64, 16, 16);   // tiles, c-groups, batch
  conv1_wavelet_k<<<g1, 256, 0, stream>>>(x, wpreT, b_pre, up);

  dim3 g2(256, 4, 16);   // tiles, co-groups, batch
  conv2_k<<<g2, 256, 0, stream>>>(up, wpostT, b_post, out);
}

// Round 5
// 677.911 us; speedup vs baseline: 3.3078x; 3.3078x over previous
//
#include <hip/hip_runtime.h>
#include <hip/hip_bf16.h>

typedef __attribute__((ext_vector_type(8))) short bf16x8;
typedef __attribute__((ext_vector_type(4))) float f32x4;
typedef __attribute__((ext_vector_type(4))) int   i32x4;

static __device__ __forceinline__ short f2bf(float f) {
  __hip_bfloat16 h = __float2bfloat16(f);
  return *reinterpret_cast<short*>(&h);
}

// ---- prep: x NCHW f32 -> xb NHWC bf16 ([16][128][128][64]) -----------------
__global__ __launch_bounds__(256) void prep_xb_k(const float* __restrict__ x,
                                                 short* __restrict__ xb) {
  int u = blockIdx.x * 256 + threadIdx.x;     // 2,097,152 units of 8 channels
  int c8  = u & 7;
  int pxl = u >> 3;                           // b*16384 + y*128 + x
  int b   = pxl >> 14;
  int yx  = pxl & 16383;
  bf16x8 r;
  #pragma unroll
  for (int j = 0; j < 8; ++j)
    r[j] = f2bf(x[(b * 64 + c8 * 8 + j) * 16384 + yx]);
  *reinterpret_cast<bf16x8*>(xb + pxl * 64 + c8 * 8) = r;
}

// ---- prep: w_pre [256][64][3][3] f32 -> wb1 [cout=256][k=576] bf16 ---------
__global__ __launch_bounds__(256) void prep_w1_k(const float* __restrict__ w,
                                                 short* __restrict__ wb) {
  int u = blockIdx.x * 256 + threadIdx.x;     // 147456
  int o = u / 576;
  int k = u - o * 576;
  int tap = k >> 6, ci = k & 63;
  wb[u] = f2bf(w[(o * 64 + ci) * 9 + tap]);
}

// ---- prep: w_post [64][64][3][3] f32 -> wb2 [64][576] bf16 -----------------
__global__ __launch_bounds__(256) void prep_w2_k(const float* __restrict__ w,
                                                 short* __restrict__ wb) {
  int u = blockIdx.x * 256 + threadIdx.x;     // 36864
  int o = u / 576;
  int k = u - o * 576;
  int tap = k >> 6, ci = k & 63;
  wb[u] = f2bf(w[(o * 64 + ci) * 9 + tap]);
}

// ---- conv1 (64->256) + wavelet combine + 2x upsample -----------------------
// Block: 256 thr (4 waves). Tile: M=64 px (one x-run of row y), N=256 couts.
// Wave w handles c-range w*16..w*16+15 across all 4 wavelet groups v.
__global__ __launch_bounds__(256) void conv1_k(
    const short* __restrict__ xb,    // [16][128][128][64] bf16
    const short* __restrict__ wb1,   // [256][576] bf16
    const float* __restrict__ b_pre, // [256] f32
    short* __restrict__ up)          // [16][256][256][64] bf16
{
  __shared__ __align__(16) char sm[25344];    // 3 rows * 66 px * 128 B
  const int tid = threadIdx.x;
  const int x0  = (blockIdx.x & 1) << 6;
  const int y   = blockIdx.y;
  const int b   = blockIdx.z;

  // stage input halo tile (reg-staged so we can swizzle the LDS dest)
  for (int u = tid; u < 1584; u += 256) {     // 3*66*8 16B-units
    int row = u / 528;
    int rem = u - row * 528;
    int px  = rem >> 3;
    int g   = rem & 7;
    int gy  = y + row - 1;
    int gx  = x0 - 1 + px;
    i32x4 v = {0, 0, 0, 0};
    if ((unsigned)gy < 128u && (unsigned)gx < 128u)
      v = *reinterpret_cast<const i32x4*>(xb + (((b << 7) + gy) << 7) * 64 + gx * 64 + g * 8);
    *reinterpret_cast<i32x4*>(sm + ((row * 66 + px) << 7) + ((g * 16) ^ ((px & 7) << 4))) = v;
  }
  __syncthreads();

  const int lane = tid & 63;
  const int wid  = tid >> 6;
  const int ln15 = lane & 15;
  const int g4   = lane >> 4;
  const int cw   = wid << 4;                  // wave c base (0,16,32,48)

  f32x4 acc[4][4];
  #pragma unroll
  for (int m = 0; m < 4; ++m)
    #pragma unroll
    for (int v = 0; v < 4; ++v)
      acc[m][v] = (f32x4){0.f, 0.f, 0.f, 0.f};

  for (int tap = 0; tap < 9; ++tap) {
    const int kh = tap / 3;
    const int kw = tap - kh * 3;
    bf16x8 bf[2][4];
    #pragma unroll
    for (int ks = 0; ks < 2; ++ks)
      #pragma unroll
      for (int v = 0; v < 4; ++v)
        bf[ks][v] = *reinterpret_cast<const bf16x8*>(
            wb1 + (v * 64 + cw + ln15) * 576 + tap * 64 + ks * 32 + g4 * 8);
    #pragma unroll
    for (int ks = 0; ks < 2; ++ks) {
      bf16x8 af[4];
      #pragma unroll
      for (int m = 0; m < 4; ++m) {
        int px = m * 16 + ln15 + kw;
        af[m] = *reinterpret_cast<const bf16x8*>(
            sm + ((kh * 66 + px) << 7) + ((ks * 64 + g4 * 16) ^ ((px & 7) << 4)));
      }
      #pragma unroll
      for (int m = 0; m < 4; ++m)
        #pragma unroll
        for (int v = 0; v < 4; ++v)
          acc[m][v] = __builtin_amdgcn_mfma_f32_16x16x32_bf16(af[m], bf[ks][v], acc[m][v], 0, 0, 0);
    }
  }

  // epilogue: bias + inverse wavelet + 2x upsample, NHWC bf16 stores
  const int c = cw + ln15;
  const float bb0 = b_pre[c], bb1 = b_pre[64 + c], bb2 = b_pre[128 + c], bb3 = b_pre[192 + c];
  #pragma unroll
  for (int m = 0; m < 4; ++m) {
    #pragma unroll
    for (int j = 0; j < 4; ++j) {
      int X   = m * 16 + g4 * 4 + j;
      int gxo = (x0 + X) << 1;
      float a0 = acc[m][0][j] + bb0;
      float a1 = acc[m][1][j] + bb1;
      float a2 = acc[m][2][j] + bb2;
      float a3 = acc[m][3][j] + bb3;
      float ee = 0.5f * (a0 + a1 + a2 + a3);
      float eo = 0.5f * (a0 - a1 + a2 - a3);
      float oe = 0.5f * (a0 + a1 - a2 - a3);
      float oo = 0.5f * (a0 - a1 - a2 + a3);
      int base0 = ((((b << 8) + (y << 1)) << 8) + gxo) * 64 + c;
      int base1 = base0 + 256 * 64;
      up[base0]      = f2bf(ee);
      up[base0 + 64] = f2bf(eo);
      up[base1]      = f2bf(oe);
      up[base1 + 64] = f2bf(oo);
    }
  }
}

// ---- conv2 (64->64) on up (NHWC bf16, 256x256) -> out NCHW f32 -------------
// Block: 256 thr (4 waves). Tile: M=128 px x N=64 couts; waves 2x2.
__global__ __launch_bounds__(256) void conv2_k(
    const short* __restrict__ up,    // [16][256][256][64] bf16
    const short* __restrict__ wb2,   // [64][576] bf16
    const float* __restrict__ b_post,
    float* __restrict__ out)         // [16][64][256][256] f32
{
  __shared__ __align__(16) char sm[49920];    // 3 rows * 130 px * 128 B
  const int tid = threadIdx.x;
  const int x0  = (blockIdx.x & 1) << 7;
  const int y   = blockIdx.y;
  const int b   = blockIdx.z;

  for (int u = tid; u < 3120; u += 256) {     // 3*130*8
    int row = u / 1040;
    int rem = u - row * 1040;
    int px  = rem >> 3;
    int g   = rem & 7;
    int gy  = y + row - 1;
    int gx  = x0 - 1 + px;
    i32x4 v = {0, 0, 0, 0};
    if ((unsigned)gy < 256u && (unsigned)gx < 256u)
      v = *reinterpret_cast<const i32x4*>(up + ((((b << 8) + gy) << 8) + gx) * 64 + g * 8);
    *reinterpret_cast<i32x4*>(sm + ((row * 130 + px) << 7) + ((g * 16) ^ ((px & 7) << 4))) = v;
  }
  __syncthreads();

  const int lane = tid & 63;
  const int wid  = tid >> 6;
  const int ln15 = lane & 15;
  const int g4   = lane >> 4;
  const int wm   = wid >> 1;                  // px half (0,1)
  const int wn   = wid & 1;                   // cout half (0,1)

  f32x4 acc[4][2];
  #pragma unroll
  for (int m = 0; m < 4; ++m)
    #pragma unroll
    for (int n = 0; n < 2; ++n)
      acc[m][n] = (f32x4){0.f, 0.f, 0.f, 0.f};

  for (int tap = 0; tap < 9; ++tap) {
    const int kh = tap / 3;
    const int kw = tap - kh * 3;
    bf16x8 bf[2][2];
    #pragma unroll
    for (int ks = 0; ks < 2; ++ks)
      #pragma unroll
      for (int n = 0; n < 2; ++n)
        bf[ks][n] = *reinterpret_cast<const bf16x8*>(
            wb2 + (wn * 32 + n * 16 + ln15) * 576 + tap * 64 + ks * 32 + g4 * 8);
    #pragma unroll
    for (int ks = 0; ks < 2; ++ks) {
      bf16x8 af[4];
      #pragma unroll
      for (int m = 0; m < 4; ++m) {
        int px = wm * 64 + m * 16 + ln15 + kw;
        af[m] = *reinterpret_cast<const bf16x8*>(
            sm + ((kh * 130 + px) << 7) + ((ks * 64 + g4 * 16) ^ ((px & 7) << 4)));
      }
      #pragma unroll
      for (int m = 0; m < 4; ++m)
        #pragma unroll
        for (int n = 0; n < 2; ++n)
          acc[m][n] = __builtin_amdgcn_mfma_f32_16x16x32_bf16(af[m], bf[ks][n], acc[m][n], 0, 0, 0);
    }
  }

  #pragma unroll
  for (int n = 0; n < 2; ++n) {
    int o = wn * 32 + n * 16 + ln15;
    float bias = b_post[o];
    #pragma unroll
    for (int m = 0; m < 4; ++m) {
      int X = x0 + wm * 64 + m * 16 + g4 * 4;
      f32x4 vv = acc[m][n] + bias;
      *reinterpret_cast<f32x4*>(out + ((b * 64 + o) * 256 + y) * 256 + X) = vv;
    }
  }
}

extern "C" void kernel_launch(void* const* d_in, const int* in_sizes, int n_in,
                              void* d_out, int out_size, void* d_ws, size_t ws_size,
                              hipStream_t stream) {
  const float* x      = (const float*)d_in[0];
  const float* w_pre  = (const float*)d_in[1];
  const float* b_pre  = (const float*)d_in[2];
  const float* w_post = (const float*)d_in[3];
  const float* b_post = (const float*)d_in[4];
  float* out = (float*)d_out;

  // xb (NHWC bf16 of x, 33.5 MB) lives at the front of d_out; it is fully
  // consumed by conv1 before conv2 overwrites d_out.
  short* xb = (short*)d_out;

  // ws: wb1 (294912 B) | wb2 (73728 B) | up bf16 (134217728 B)  = 134.6 MB
  char* ws = (char*)d_ws;
  short* wb1 = (short*)ws;
  short* wb2 = (short*)(ws + 294912);
  short* up  = (short*)(ws + 294912 + 73728);

  prep_xb_k<<<8192, 256, 0, stream>>>(x, xb);
  prep_w1_k<<<576, 256, 0, stream>>>(w_pre, wb1);
  prep_w2_k<<<144, 256, 0, stream>>>(w_post, wb2);

  dim3 g1(2, 128, 16);
  conv1_k<<<g1, 256, 0, stream>>>(xb, wb1, b_pre, up);

  dim3 g2(2, 256, 16);
  conv2_k<<<g2, 256, 0, stream>>>(up, wb2, b_post, out);
}

// Round 7
// 606.352 us; speedup vs baseline: 3.6981x; 1.1180x over previous
//
#include <hip/hip_runtime.h>
#include <hip/hip_bf16.h>

typedef __attribute__((ext_vector_type(8))) short bf16x8;
typedef __attribute__((ext_vector_type(4))) float f32x4;
typedef __attribute__((ext_vector_type(4))) int   i32x4;

static __device__ __forceinline__ short f2bf(float f) {
  __hip_bfloat16 h = __float2bfloat16(f);
  return *reinterpret_cast<short*>(&h);
}

// ---- prep: x NCHW f32 -> xb NHWC bf16 ([16][128][128][64]) -----------------
__global__ __launch_bounds__(256) void prep_xb_k(const float* __restrict__ x,
                                                 short* __restrict__ xb) {
  int u = blockIdx.x * 256 + threadIdx.x;     // 2,097,152 units of 8 channels
  int c8  = u & 7;
  int pxl = u >> 3;                           // b*16384 + y*128 + x
  int b   = pxl >> 14;
  int yx  = pxl & 16383;
  bf16x8 r;
  #pragma unroll
  for (int j = 0; j < 8; ++j)
    r[j] = f2bf(x[(b * 64 + c8 * 8 + j) * 16384 + yx]);
  *reinterpret_cast<bf16x8*>(xb + pxl * 64 + c8 * 8) = r;
}

// ---- prep: w_pre [256][64][3][3] f32 -> wb1 [cout=256][k=576] bf16 ---------
__global__ __launch_bounds__(256) void prep_w1_k(const float* __restrict__ w,
                                                 short* __restrict__ wb) {
  int u = blockIdx.x * 256 + threadIdx.x;     // 147456
  int o = u / 576;
  int k = u - o * 576;
  int tap = k >> 6, ci = k & 63;
  wb[u] = f2bf(w[(o * 64 + ci) * 9 + tap]);
}

// ---- prep: w_post [64][64][3][3] f32 -> wb2 [64][576] bf16 -----------------
__global__ __launch_bounds__(256) void prep_w2_k(const float* __restrict__ w,
                                                 short* __restrict__ wb) {
  int u = blockIdx.x * 256 + threadIdx.x;     // 36864
  int o = u / 576;
  int k = u - o * 576;
  int tap = k >> 6, ci = k & 63;
  wb[u] = f2bf(w[(o * 64 + ci) * 9 + tap]);
}

// ---- conv1 (64->256) + wavelet combine + 2x upsample -----------------------
// Block: 256 thr (4 waves). Tile: 4 output rows x 64 px, N=256 couts.
// LDS: 6 halo rows x 66 px x 128 B. Wave w owns c-range w*16..w*16+15 across
// the 4 wavelet groups, looping over the 4 output rows (stage reused 4x).
__global__ __launch_bounds__(256) void conv1_k(
    const short* __restrict__ xb,    // [16][128][128][64] bf16
    const short* __restrict__ wb1,   // [256][576] bf16
    const float* __restrict__ b_pre, // [256] f32
    short* __restrict__ up)          // [16][256][256][64] bf16
{
  __shared__ __align__(16) char sm[50688];    // 6 rows * 66 px * 128 B
  const int tid = threadIdx.x;
  const int x0  = blockIdx.x << 6;            // 0,64
  const int y0  = blockIdx.y << 2;            // 4-row tile base
  const int b   = blockIdx.z;

  // stage 6-row halo tile (reg-staged, swizzled LDS dest)
  for (int u = tid; u < 3168; u += 256) {     // 6*66*8 16B-units
    int row = u / 528;
    int rem = u - row * 528;
    int px  = rem >> 3;
    int g   = rem & 7;
    int gy  = y0 + row - 1;
    int gx  = x0 - 1 + px;
    i32x4 v = {0, 0, 0, 0};
    if ((unsigned)gy < 128u && (unsigned)gx < 128u)
      v = *reinterpret_cast<const i32x4*>(xb + (((b << 7) + gy) << 7) * 64 + gx * 64 + g * 8);
    *reinterpret_cast<i32x4*>(sm + ((row * 66 + px) << 7) + ((g * 16) ^ ((px & 7) << 4))) = v;
  }
  __syncthreads();

  const int lane = tid & 63;
  const int wid  = tid >> 6;
  const int ln15 = lane & 15;
  const int g4   = lane >> 4;
  const int cw   = wid << 4;                  // wave c base (0,16,32,48)
  const int c    = cw + ln15;
  const float bb0 = b_pre[c], bb1 = b_pre[64 + c], bb2 = b_pre[128 + c], bb3 = b_pre[192 + c];

  for (int r = 0; r < 4; ++r) {
    f32x4 acc[4][4];
    #pragma unroll
    for (int m = 0; m < 4; ++m)
      #pragma unroll
      for (int v = 0; v < 4; ++v)
        acc[m][v] = (f32x4){0.f, 0.f, 0.f, 0.f};

    for (int tap = 0; tap < 9; ++tap) {
      const int kh = tap / 3;
      const int kw = tap - kh * 3;
      bf16x8 bf[2][4];
      #pragma unroll
      for (int ks = 0; ks < 2; ++ks)
        #pragma unroll
        for (int v = 0; v < 4; ++v)
          bf[ks][v] = *reinterpret_cast<const bf16x8*>(
              wb1 + (v * 64 + cw + ln15) * 576 + tap * 64 + ks * 32 + g4 * 8);
      #pragma unroll
      for (int ks = 0; ks < 2; ++ks) {
        bf16x8 af[4];
        #pragma unroll
        for (int m = 0; m < 4; ++m) {
          int px = m * 16 + ln15 + kw;
          af[m] = *reinterpret_cast<const bf16x8*>(
              sm + (((r + kh) * 66 + px) << 7) + ((ks * 64 + g4 * 16) ^ ((px & 7) << 4)));
        }
        #pragma unroll
        for (int m = 0; m < 4; ++m)
          #pragma unroll
          for (int v = 0; v < 4; ++v)
            acc[m][v] = __builtin_amdgcn_mfma_f32_16x16x32_bf16(af[m], bf[ks][v], acc[m][v], 0, 0, 0);
      }
    }

    // epilogue: bias + inverse wavelet + 2x upsample, NHWC bf16 stores
    const int py = (y0 + r) << 1;
    #pragma unroll
    for (int m = 0; m < 4; ++m) {
      #pragma unroll
      for (int j = 0; j < 4; ++j) {
        int X   = m * 16 + g4 * 4 + j;
        int gxo = (x0 + X) << 1;
        float a0 = acc[m][0][j] + bb0;
        float a1 = acc[m][1][j] + bb1;
        float a2 = acc[m][2][j] + bb2;
        float a3 = acc[m][3][j] + bb3;
        float ee = 0.5f * (a0 + a1 + a2 + a3);
        float eo = 0.5f * (a0 - a1 + a2 - a3);
        float oe = 0.5f * (a0 + a1 - a2 - a3);
        float oo = 0.5f * (a0 - a1 - a2 + a3);
        int base0 = ((((b << 8) + py) << 8) + gxo) * 64 + c;
        int base1 = base0 + 256 * 64;
        up[base0]      = f2bf(ee);
        up[base0 + 64] = f2bf(eo);
        up[base1]      = f2bf(oe);
        up[base1 + 64] = f2bf(oo);
      }
    }
  }
}

// ---- conv2 (64->64) on up (NHWC bf16, 256x256) -> out NCHW f32 -------------
// Block: 256 thr (4 waves). Tile: 4 output rows x 64 px, N=64 couts.
// LDS: 6 halo rows x 66 px x 128 B. Wave w computes row w (all 64 couts).
__global__ __launch_bounds__(256) void conv2_k(
    const short* __restrict__ up,    // [16][256][256][64] bf16
    const short* __restrict__ wb2,   // [64][576] bf16
    const float* __restrict__ b_post,
    float* __restrict__ out)         // [16][64][256][256] f32
{
  __shared__ __align__(16) char sm[50688];    // 6 rows * 66 px * 128 B
  const int tid = threadIdx.x;
  const int x0  = blockIdx.x << 6;            // 0,64,128,192
  const int y0  = blockIdx.y << 2;
  const int b   = blockIdx.z;

  for (int u = tid; u < 3168; u += 256) {     // 6*66*8
    int row = u / 528;
    int rem = u - row * 528;
    int px  = rem >> 3;
    int g   = rem & 7;
    int gy  = y0 + row - 1;
    int gx  = x0 - 1 + px;
    i32x4 v = {0, 0, 0, 0};
    if ((unsigned)gy < 256u && (unsigned)gx < 256u)
      v = *reinterpret_cast<const i32x4*>(up + ((((b << 8) + gy) << 8) + gx) * 64 + g * 8);
    *reinterpret_cast<i32x4*>(sm + ((row * 66 + px) << 7) + ((g * 16) ^ ((px & 7) << 4))) = v;
  }
  __syncthreads();

  const int lane = tid & 63;
  const int wid  = tid >> 6;                  // wave = output row r
  const int ln15 = lane & 15;
  const int g4   = lane >> 4;
  const int r    = wid;

  f32x4 acc[4][4];
  #pragma unroll
  for (int m = 0; m < 4; ++m)
    #pragma unroll
    for (int n = 0; n < 4; ++n)
      acc[m][n] = (f32x4){0.f, 0.f, 0.f, 0.f};

  for (int tap = 0; tap < 9; ++tap) {
    const int kh = tap / 3;
    const int kw = tap - kh * 3;
    bf16x8 bf[2][4];
    #pragma unroll
    for (int ks = 0; ks < 2; ++ks)
      #pragma unroll
      for (int n = 0; n < 4; ++n)
        bf[ks][n] = *reinterpret_cast<const bf16x8*>(
            wb2 + (n * 16 + ln15) * 576 + tap * 64 + ks * 32 + g4 * 8);
    #pragma unroll
    for (int ks = 0; ks < 2; ++ks) {
      bf16x8 af[4];
      #pragma unroll
      for (int m = 0; m < 4; ++m) {
        int px = m * 16 + ln15 + kw;
        af[m] = *reinterpret_cast<const bf16x8*>(
            sm + (((r + kh) * 66 + px) << 7) + ((ks * 64 + g4 * 16) ^ ((px & 7) << 4)));
      }
      #pragma unroll
      for (int m = 0; m < 4; ++m)
        #pragma unroll
        for (int n = 0; n < 4; ++n)
          acc[m][n] = __builtin_amdgcn_mfma_f32_16x16x32_bf16(af[m], bf[ks][n], acc[m][n], 0, 0, 0);
    }
  }

  const int y = y0 + r;
  #pragma unroll
  for (int n = 0; n < 4; ++n) {
    int o = n * 16 + ln15;
    float bias = b_post[o];
    #pragma unroll
    for (int m = 0; m < 4; ++m) {
      int X = x0 + m * 16 + g4 * 4;
      f32x4 vv = acc[m][n] + bias;
      *reinterpret_cast<f32x4*>(out + ((b * 64 + o) * 256 + y) * 256 + X) = vv;
    }
  }
}

extern "C" void kernel_launch(void* const* d_in, const int* in_sizes, int n_in,
                              void* d_out, int out_size, void* d_ws, size_t ws_size,
                              hipStream_t stream) {
  const float* x      = (const float*)d_in[0];
  const float* w_pre  = (const float*)d_in[1];
  const float* b_pre  = (const float*)d_in[2];
  const float* w_post = (const float*)d_in[3];
  const float* b_post = (const float*)d_in[4];
  float* out = (float*)d_out;

  // xb (NHWC bf16 of x, 33.5 MB) lives at the front of d_out; it is fully
  // consumed by conv1 before conv2 overwrites d_out.
  short* xb = (short*)d_out;

  // ws: wb1 (294912 B) | wb2 (73728 B) | up bf16 (134217728 B)  = 134.6 MB
  char* ws = (char*)d_ws;
  short* wb1 = (short*)ws;
  short* wb2 = (short*)(ws + 294912);
  short* up  = (short*)(ws + 294912 + 73728);

  prep_xb_k<<<8192, 256, 0, stream>>>(x, xb);
  prep_w1_k<<<576, 256, 0, stream>>>(w_pre, wb1);
  prep_w2_k<<<144, 256, 0, stream>>>(w_post, wb2);

  dim3 g1(2, 32, 16);    // x-tiles(64px), y-tiles(4 rows), batch
  conv1_k<<<g1, 256, 0, stream>>>(xb, wb1, b_pre, up);

  dim3 g2(4, 64, 16);    // x-tiles(64px), y-tiles(4 rows), batch
  conv2_k<<<g2, 256, 0, stream>>>(up, wb2, b_post, out);
}